// Round 4
// baseline (123.634 us; speedup 1.0000x reference)
//
#include <hip/hip_runtime.h>

// filtfilt butter(4,0.2), 512 rows x T=32768 fp32.  R8: R7 + intra-wave pipeline.
//  - R7 (LDS-coalesced, fp16 staging, XOR swizzle) cut kernel 48.5 -> ~36us, but
//    the grid was ONE lockstep generation (32 waves/CU): every wave did
//    [load burst | 2500cy compute, memory idle | store burst] in phase ->
//    T ~= reads + compute + writes serially (10.3 + 8 + 10.2 + ramp ~= 36us).
//  - R8: each wave owns TWO consecutive 2048-seg (A,B). ALL global loads issued
//    at kernel top (sched_barrier(0) pins them); compute A while B's loads fly;
//    store A drains under compute B. Counted vmcnt (compiler, per-register)
//    keeps B's loads outstanding across stage/compute A. Single LDS slice
//    reused A->B (wave-order DS + may-alias forbids reordering).
//  - A's post region == B's head: one edge load saved.
//  - per-segment math identical to R7: fwd warm-up 32 (neighbor chunk in LDS),
//    Y over X in place, bwd warm-up 28 from neighbor lane's Y, lane-63 seam,
//    exact odd-ext at both signal ends. fp16 LDS data: absmax 0.0156 (thr 7e-2).
//  - launch_bounds(256,4): cap 128 VGPR (peak live ~90) -- no forced spill (R5).
//    Grid 1024 blocks x 4 waves = 4096 waves = 16/CU, one generation.

typedef __fp16 h4 __attribute__((ext_vector_type(4)));
typedef __fp16 h8 __attribute__((ext_vector_type(8)));

constexpr int kT      = 32768;
constexpr int kSeg    = 2048;          // samples per segment
constexpr int kNSeg   = kT / kSeg;     // 16 segments/row; 8 spans/row (2 seg/wave)
constexpr int kTPB    = 256;           // 4 waves / block
constexpr int kSliceB = 4224;          // 64B pre + 4096B main + 64B post

#define B0 0.0048243445989025905f
#define B1 0.019297378395610362f
#define B2 0.028946067593415543f
#define B3 0.019297378395610362f
#define B4 0.0048243445989025905f
#define NA1 2.369513007182038f
#define NA2 (-2.3139884144002064f)
#define NA3 1.0546654058785661f
#define NA4 (-0.18737949236818502f)

#define STEPF(xv) do { \
    y  = fmaf(B0, (xv), z1); \
    z1 = fmaf(NA1, y, fmaf(B1, (xv), z2)); \
    z2 = fmaf(NA2, y, fmaf(B2, (xv), z3)); \
    z3 = fmaf(NA3, y, fmaf(B3, (xv), z4)); \
    z4 = fmaf(NA4, y, B4 * (xv)); \
} while (0)

#define PK(a, b) __builtin_bit_cast(int, __builtin_amdgcn_cvt_pkrtz((a), (b)))

__device__ __forceinline__ int swz(int lo) { return lo ^ (((lo >> 7) & 7) << 4); }

__device__ __forceinline__ void process_seg(
    char* __restrict__ Lb, const int l,
    const float4 (&mv)[8], const float4 pre4, const float4 post4,
    const bool haspre, const bool haspost, float* __restrict__ outr)
{
    // ---------------- stage: registers -> fp16 LDS ----------------
    #pragma unroll
    for (int i = 0; i < 8; ++i) {
        int lo = swz(64 + i * 512 + 8 * l);
        int2 wi = { PK(mv[i].x, mv[i].y), PK(mv[i].z, mv[i].w) };
        *(int2*)(Lb + lo) = wi;
    }
    if (l < 8) {
        if (haspre) {                            // pre slot: x[sb-32, sb)
            int2 wi = { PK(pre4.x, pre4.y), PK(pre4.z, pre4.w) };
            *(int2*)(Lb + 8 * l) = wi;           // [0,64): identity under swz
        }
        if (haspost) {                           // post slot: x[sb+2048, +32)
            int2 wi = { PK(post4.x, post4.y), PK(post4.z, post4.w) };
            *(int2*)(Lb + 4160 + 8 * l) = wi;    // identity under swz
        }
    }
    asm volatile("s_waitcnt lgkmcnt(0)" ::: "memory");
    if (!haspre && l < 8) {
        // seg 0: pre = 17 zeros + 15 left odd-ext (exact; zero-IC-preserving pad)
        const __fp16* xs = (const __fp16*)(Lb + 64);   // samples 0..31, identity
        float x0 = (float)xs[0];
        float v[4];
        #pragma unroll
        for (int r = 0; r < 4; ++r) {
            int k = 4 * l + r;
            v[r] = (k < 17) ? 0.f : fmaf(2.f, x0, -(float)xs[32 - k]);
        }
        int2 wi = { PK(v[0], v[1]), PK(v[2], v[3]) };
        *(int2*)(Lb + 8 * l) = wi;
    }
    asm volatile("" ::: "memory");

    // ---------------- phase 1: fwd warm-up (32, chunk l-1 / pre) ----------
    float z1 = 0.f, z2 = 0.f, z3 = 0.f, z4 = 0.f, y;
    {
        const int wb = l * 64;
        const int xv = ((wb >> 7) & 7) << 4;
        #pragma unroll
        for (int j = 0; j < 4; ++j) {
            h8 v = *(const h8*)(Lb + ((wb + 16 * j) ^ xv));
            #pragma unroll
            for (int e = 0; e < 8; ++e) STEPF((float)v[e]);
        }
    }

    // ---------------- phase 2: fwd main (32), Y over X in place -----------
    h8 tailA, tailB;    // raw X samples 16..31 of own chunk (for last-seg ext)
    {
        const int mb = (l + 1) * 64;
        const int xm = ((mb >> 7) & 7) << 4;
        #pragma unroll
        for (int j = 0; j < 4; ++j) {
            char* p = Lb + ((mb + 16 * j) ^ xm);
            h8 v = *(const h8*)p;
            if (j == 2) tailA = v;
            if (j == 3) tailB = v;
            float q[8];
            #pragma unroll
            for (int e = 0; e < 8; ++e) { STEPF((float)v[e]); q[e] = y; }
            int4 wi = { PK(q[0], q[1]), PK(q[2], q[3]), PK(q[4], q[5]), PK(q[6], q[7]) };
            *(int4*)p = wi;
        }
    }

    // ------ phase 2.5 (lane 63 only): build W into post region ------------
    if (l == 63) {
        if (haspost) {
            // continue fwd chain over post X (28 steps), write y -> post
            #pragma unroll
            for (int g = 0; g < 4; ++g) {
                h8 v = *(const h8*)(Lb + 4160 + 16 * g);
                if (g < 3) {
                    float q[8];
                    #pragma unroll
                    for (int e = 0; e < 8; ++e) { STEPF((float)v[e]); q[e] = y; }
                    int4 wi = { PK(q[0], q[1]), PK(q[2], q[3]), PK(q[4], q[5]), PK(q[6], q[7]) };
                    *(int4*)(Lb + 4160 + 16 * g) = wi;
                } else {
                    float q[4];
                    #pragma unroll
                    for (int e = 0; e < 4; ++e) { STEPF((float)v[e]); q[e] = y; }
                    int4 wi = { PK(q[0], q[1]), PK(q[2], q[3]), 0, 0 };
                    *(int4*)(Lb + 4160 + 16 * g) = wi;
                }
            }
        } else {
            // last seg: 15 exact right odd-ext y (continue chain), zero-padded
            float xl = (float)tailB[7];
            float q[8];
            #pragma unroll
            for (int j = 0; j < 8; ++j) {
                float xe = fmaf(2.f, xl, -(float)(j < 7 ? tailB[6 - j] : tailA[14 - j]));
                STEPF(xe); q[j] = y;
            }
            int4 w0 = { PK(q[0], q[1]), PK(q[2], q[3]), PK(q[4], q[5]), PK(q[6], q[7]) };
            *(int4*)(Lb + 4160) = w0;
            float r[7];
            #pragma unroll
            for (int j = 8; j < 15; ++j) {
                float xe = fmaf(2.f, xl, -(float)tailA[14 - j]);
                STEPF(xe); r[j - 8] = y;
            }
            int4 w1 = { PK(r[0], r[1]), PK(r[2], r[3]), PK(r[4], r[5]), PK(r[6], 0.f) };
            *(int4*)(Lb + 4176) = w1;
            int4 zz = {0, 0, 0, 0};
            *(int4*)(Lb + 4192) = zz;
            *(int4*)(Lb + 4208) = zz;
        }
    }
    asm volatile("" ::: "memory");

    // ------- phase 3: bwd warm-up (28, neighbor Y / post W, descending) ---
    z1 = z2 = z3 = z4 = 0.f;
    {
        const int bb = (l + 2) * 64;
        const int xb = ((bb >> 7) & 7) << 4;
        h8 w3v = *(const h8*)(Lb + ((bb + 48) ^ xb));
        h8 w2v = *(const h8*)(Lb + ((bb + 32) ^ xb));
        h8 w1v = *(const h8*)(Lb + ((bb + 16) ^ xb));
        h8 w0v = *(const h8*)(Lb + ((bb +  0) ^ xb));
        STEPF((float)w3v[3]); STEPF((float)w3v[2]);
        STEPF((float)w3v[1]); STEPF((float)w3v[0]);
        #pragma unroll
        for (int e = 7; e >= 0; --e) STEPF((float)w2v[e]);
        #pragma unroll
        for (int e = 7; e >= 0; --e) STEPF((float)w1v[e]);
        #pragma unroll
        for (int e = 7; e >= 0; --e) STEPF((float)w0v[e]);
    }

    // ------- phase 4: bwd main (32, descending), out over Y in place ------
    {
        const int mb = (l + 1) * 64;
        const int xm = ((mb >> 7) & 7) << 4;
        #pragma unroll
        for (int j = 3; j >= 0; --j) {
            char* p = Lb + ((mb + 16 * j) ^ xm);
            h8 v = *(const h8*)p;
            float q[8];
            #pragma unroll
            for (int e = 7; e >= 0; --e) { STEPF((float)v[e]); q[e] = y; }
            int4 wi = { PK(q[0], q[1]), PK(q[2], q[3]), PK(q[4], q[5]), PK(q[6], q[7]) };
            *(int4*)p = wi;
        }
    }
    asm volatile("" ::: "memory");

    // ---------------- phase 5: coalesced fp16 LDS -> fp32 global ----------
    float4* op = (float4*)outr;
    #pragma unroll
    for (int i = 0; i < 8; ++i) {
        int lo = swz(64 + i * 512 + 8 * l);
        h4 hv = *(const h4*)(Lb + lo);
        float4 o = { (float)hv[0], (float)hv[1], (float)hv[2], (float)hv[3] };
        op[i * 64 + l] = o;
    }
}

__global__ __launch_bounds__(kTPB, 4)
void filtfilt_kernel(const float* __restrict__ x, float* __restrict__ out) {
    __shared__ __align__(16) char lds[4 * kSliceB];
    const int t  = threadIdx.x;
    const int l  = t & 63;                       // lane == chunk index in segment
    const int wv = t >> 6;
    const int W  = blockIdx.x * 4 + wv;          // global span id
    const int row = W >> 3;                      // 8 spans/row
    const int sp  = W & 7;
    const int segA = 2 * sp;                     // A = [segA], B = [segA+1]
    const float* __restrict__ xrA = x + (size_t)row * kT + segA * kSeg;
    const float* __restrict__ xrB = xrA + kSeg;
    float* __restrict__ orA = out + (size_t)row * kT + segA * kSeg;
    float* __restrict__ orB = orA + kSeg;
    char* Lb = lds + wv * kSliceB;
    const bool preA  = (segA > 0);               // seg0 only when sp==0
    const bool postB = (sp < 7);                 // segB==15 has no post

    // ---- issue ALL global loads up front (A first, then B) ----
    const float4* xpA = (const float4*)xrA;
    const float4* xpB = (const float4*)xrB;
    float4 mvA[8], mvB[8];
    #pragma unroll
    for (int i = 0; i < 8; ++i) mvA[i] = xpA[i * 64 + l];
    float4 preA4 = {0.f,0.f,0.f,0.f}, postA4 = {0.f,0.f,0.f,0.f};
    float4 preB4 = {0.f,0.f,0.f,0.f}, postB4 = {0.f,0.f,0.f,0.f};
    if (l < 8) {
        if (preA) preA4 = *(const float4*)(xrA - 32 + l * 4);
        postA4 = *(const float4*)(xrA + kSeg + l * 4);   // B's head (always exists)
        preB4  = *(const float4*)(xrB - 32 + l * 4);     // A's tail (always exists)
    }
    #pragma unroll
    for (int i = 0; i < 8; ++i) mvB[i] = xpB[i * 64 + l];
    if (l < 8) {
        if (postB) postB4 = *(const float4*)(xrB + kSeg + l * 4);
    }
    __builtin_amdgcn_sched_barrier(0);   // pin load issue before any compute

    // ---- pipeline: compute A (B loads in flight), then B (A stores drain) ----
    process_seg(Lb, l, mvA, preA4, postA4, preA, true,  orA);
    process_seg(Lb, l, mvB, preB4, postB4, true,  postB, orB);
}

extern "C" void kernel_launch(void* const* d_in, const int* in_sizes, int n_in,
                              void* d_out, int out_size, void* d_ws, size_t ws_size,
                              hipStream_t stream) {
    const float* x = (const float*)d_in[0];
    float* outp    = (float*)d_out;
    const int rows   = in_sizes[0] / kT;                  // 512
    const int blocks = rows * (kNSeg / 2) * 64 / kTPB;    // 1024
    filtfilt_kernel<<<blocks, kTPB, 0, stream>>>(x, outp);
}